// Round 14
// baseline (2011.135 us; speedup 1.0000x reference)
//
#include <hip/hip_runtime.h>
#include <cstdint>
#include <cstddef>

typedef unsigned short ushort_t;
typedef unsigned int uint_t;

#define NATOMS 8000
#define NEDGES 100000
#define NTRIP  500000
#define NGRAPH 64
#define HD     128
#define NRR    6
#define NSNR   42
#define NBB    8
#define NBLKS  6
#define MSZ    16384

using short8   = __attribute__((ext_vector_type(8))) short;
using ushort8v = __attribute__((ext_vector_type(8))) unsigned short;
using floatx4  = __attribute__((ext_vector_type(4))) float;
using float2v  = __attribute__((ext_vector_type(2))) float;

__device__ __forceinline__ float siluf(float x){ return x / (1.f + __expf(-x)); }
__device__ __forceinline__ ushort_t f2us(float f){
    uint_t u = __builtin_bit_cast(uint_t, f);
    u = (u + 0x7FFFu + ((u >> 16) & 1u)) >> 16;
    return (ushort_t)u;
}
__device__ __forceinline__ float us2f(ushort_t s){
    uint_t u = ((uint_t)s) << 16;
    return __builtin_bit_cast(float, u);
}
__device__ __forceinline__ void wave_lds_fence(){
    asm volatile("s_waitcnt lgkmcnt(0)" ::: "memory");
}
__device__ __forceinline__ short8 ldfrag(const ushort_t* W, int frag, int lane){
    return *(const short8*)(W + ((size_t)(frag * 64 + lane) << 3));
}

__global__ void zerof_k(float* __restrict__ p, int n){ int i=blockIdx.x*256+threadIdx.x; if(i<n) p[i]=0.f; }
__global__ void zeroi_k(int* __restrict__ p, int n){ int i=blockIdx.x*256+threadIdx.x; if(i<n) p[i]=0; }

// ---------------- weight prep ----------------
__global__ __launch_bounds__(256)
void transp128_k(const float* __restrict__ src, ushort_t* __restrict__ dst)
{
    __shared__ ushort_t L[128][130];
    int m = blockIdx.x;
    const float* S = src + (size_t)m * MSZ;
    ushort_t* D = dst + (size_t)m * MSZ;
    int tid = threadIdx.x;
    #pragma unroll
    for (int p = 0; p < 64; ++p) {
        int idx = p * 256 + tid;
        int k = idx >> 7, n = idx & 127;
        L[k][n] = f2us(S[idx]);
    }
    __syncthreads();
    #pragma unroll
    for (int p = 0; p < 64; ++p) {
        int idx = p * 256 + tid;
        int n = idx >> 7, k = idx & 127;
        D[idx] = L[k][n];
    }
}

// fragment order (K=128)
__global__ __launch_bounds__(256)
void transp128s_k(const float* __restrict__ src, ushort_t* __restrict__ dst)
{
    int m = blockIdx.x;
    const float* S = src + (size_t)m * MSZ;
    ushort_t* D = dst + (size_t)m * MSZ;
    int tid = threadIdx.x;
    #pragma unroll
    for (int p = 0; p < 64; ++p) {
        int idx = p * 256 + tid;
        int k = idx >> 7, n = idx & 127;
        size_t d = ((size_t)(((k >> 5) * 8 + (n >> 4)) * 64 + ((k >> 3) & 3) * 16 + (n & 15)) << 3)
                   + (k & 7);
        D[d] = f2us(S[idx]);
    }
}

// int_W -> fragment order (K=1024)
__global__ void castWMs_k(const float* __restrict__ src, ushort_t* __restrict__ dst, int n)
{
    int i = blockIdx.x * 256 + threadIdx.x;
    if (i >= n) return;
    int b = i >> 17;
    int r = i & 131071;
    int nn = r >> 10, k = r & 1023;
    size_t d = (size_t)b * 131072
             + ((size_t)(((k >> 5) * 8 + (nn >> 4)) * 64 + ((k >> 3) & 3) * 16 + (nn & 15)) << 3)
             + (k & 7);
    dst[d] = f2us(src[i]);
}

__global__ void pack_bc_k(const float* __restrict__ bef, const float* __restrict__ lin,
                          const float* __restrict__ aft, float* __restrict__ bc)
{
    int b = blockIdx.x;
    for (int i = threadIdx.x; i < 7 * HD; i += 256) {
        int s = i >> 7, h = i & 127;
        float v;
        if (s < 2)      v = bef[(size_t)(b * 2 + s) * HD + h];
        else if (s == 2) v = lin[(size_t)b * HD + h];
        else             v = aft[(size_t)(b * 4 + (s - 3)) * HD + h];
        bc[(size_t)b * 7 * HD + i] = v;
    }
}

// ---------------- CSR build ----------------
__global__ void hist_k(const int* __restrict__ idx, int n, int* __restrict__ cnt)
{
    int i = blockIdx.x * 256 + threadIdx.x;
    if (i < n) atomicAdd(&cnt[idx[i]], 1);
}
__global__ void blksum_k(const int* __restrict__ c, int n, int* __restrict__ bs)
{
    int i = blockIdx.x * 256 + threadIdx.x;
    int v = (i < n) ? c[i] : 0;
    #pragma unroll
    for (int off = 32; off; off >>= 1) v += __shfl_down(v, off);
    __shared__ int sh[4];
    if ((threadIdx.x & 63) == 0) sh[threadIdx.x >> 6] = v;
    __syncthreads();
    if (threadIdx.x == 0) bs[blockIdx.x] = sh[0] + sh[1] + sh[2] + sh[3];
}
__global__ void scanb_k(int* __restrict__ bs, int nb)
{
    __shared__ int sh[1024];
    int t = threadIdx.x;
    int v = (t < nb) ? bs[t] : 0;
    sh[t] = v; __syncthreads();
    for (int off = 1; off < 1024; off <<= 1) {
        int u = (t >= off) ? sh[t - off] : 0;
        __syncthreads();
        sh[t] += u;
        __syncthreads();
    }
    if (t < nb) bs[t] = sh[t] - v;
}
__global__ void scanfin_k(const int* __restrict__ c, int n, const int* __restrict__ bs,
                          int* __restrict__ offs)
{
    __shared__ int sh[256];
    int t = threadIdx.x;
    int i = blockIdx.x * 256 + t;
    int v = (i < n) ? c[i] : 0;
    sh[t] = v; __syncthreads();
    for (int off = 1; off < 256; off <<= 1) {
        int u = (t >= off) ? sh[t - off] : 0;
        __syncthreads();
        sh[t] += u;
        __syncthreads();
    }
    if (i < n)  offs[i] = bs[blockIdx.x] + sh[t] - v;
    if (i == n - 1) offs[n] = bs[blockIdx.x] + sh[t];
}
__global__ void fill_k(const int* __restrict__ idx, int n, const int* __restrict__ offs,
                       int* __restrict__ cur, int* __restrict__ sorted)
{
    int i = blockIdx.x * 256 + threadIdx.x;
    if (i >= n) return;
    int e = idx[i];
    int p = offs[e] + atomicAdd(&cur[e], 1);
    sorted[p] = i;
}
__global__ void invperm_k(const int* __restrict__ tsorted, const int* __restrict__ idx_kj,
                          int* __restrict__ tpos, int* __restrict__ ekjs, int n)
{
    int k = blockIdx.x * 256 + threadIdx.x;
    if (k >= n) return;
    int t = tsorted[k];
    tpos[t] = k;
    ekjs[k] = idx_kj[t];
}

// ---------------------------------------------------------------------------
// Legacy block helpers (emb_chain only)
// ---------------------------------------------------------------------------
__device__ __forceinline__ void load_bh(const ushort_t* Bt, int kh, int tid, ushort8v r[4])
{
    #pragma unroll
    for (int p = 0; p < 4; ++p) {
        int c = p * 256 + tid;
        int n = c >> 3, c8 = c & 7;
        r[p] = *(const ushort8v*)(Bt + (size_t)n * 128 + kh * 64 + c8 * 8);
    }
}
__device__ __forceinline__ void store_bh(ushort8v r[4], ushort_t (*Bl)[72], int tid)
{
    #pragma unroll
    for (int p = 0; p < 4; ++p) {
        int c = p * 256 + tid;
        *(ushort8v*)&Bl[c >> 3][(c & 7) * 8] = r[p];
    }
}
__device__ __forceinline__ void mfma_kh(ushort_t (*Al)[136], ushort_t (*Bl)[72],
                                        floatx4 acc[4][4], int kh,
                                        int wr, int wc, int lhi, int llo)
{
    #pragma unroll
    for (int ks = 0; ks < 2; ++ks) {
        int kk = ks * 32 + lhi * 8;
        short8 af[4], bf[4];
        #pragma unroll
        for (int tm = 0; tm < 4; ++tm)
            af[tm] = *(const short8*)&Al[wr * 64 + tm * 16 + llo][kh * 64 + kk];
        #pragma unroll
        for (int tn = 0; tn < 4; ++tn)
            bf[tn] = *(const short8*)&Bl[wc * 64 + tn * 16 + llo][kk];
        #pragma unroll
        for (int tm = 0; tm < 4; ++tm)
            #pragma unroll
            for (int tn = 0; tn < 4; ++tn)
                acc[tm][tn] = __builtin_amdgcn_mfma_f32_16x16x32_bf16(
                    af[tm], bf[tn], acc[tm][tn], 0, 0, 0);
    }
}
#define ZERO_ACC4(acc) { _Pragma("unroll") for (int a_=0;a_<4;++a_) _Pragma("unroll") \
    for (int b_=0;b_<4;++b_) _Pragma("unroll") for (int q_=0;q_<4;++q_) acc[a_][b_][q_]=0.f; }
#define ZERO_ACC8(acc) { _Pragma("unroll") for (int t_=0;t_<8;++t_) { acc[t_][0]=0.f; acc[t_][1]=0.f; acc[t_][2]=0.f; acc[t_][3]=0.f; } }

// ---------------------------------------------------------------------------
// Embedding chain (block-tiled, classic weight layout)
// ---------------------------------------------------------------------------
__global__ __launch_bounds__(256)
void emb_chain_k(const float* __restrict__ rbf, const float* __restrict__ W6g,
                 const float* __restrict__ b6g, const ushort_t* __restrict__ Wemb3,
                 const float* __restrict__ A0, const float* __restrict__ A1,
                 const float* __restrict__ emb_b, const int* __restrict__ z,
                 const int* __restrict__ ii, const int* __restrict__ jj,
                 float* __restrict__ X, ushort_t* __restrict__ Xb, int M)
{
    __shared__ ushort_t Al[128][136];
    __shared__ ushort_t Bl[128][72];
    __shared__ float W6[NRR * HD];
    __shared__ float b6s[HD];
    const int tid = threadIdx.x, row0 = blockIdx.x * 128;
    const int wave = tid >> 6, lane = tid & 63;
    const int wr = wave >> 1, wc_ = wave & 1, lhi = lane >> 4, llo = lane & 15;

    for (int i = tid; i < NRR * HD; i += 256) W6[i] = W6g[i];
    if (tid < HD) b6s[tid] = b6g[tid];
    ushort8v r0[4], r1[4];
    load_bh(Wemb3, 0, tid, r0); load_bh(Wemb3, 1, tid, r1);
    __syncthreads();

    {
        int e_l = tid >> 1, half = tid & 1;
        int grow = row0 + e_l; if (grow >= M) grow = M - 1;
        float r6[NRR];
        #pragma unroll
        for (int r = 0; r < NRR; ++r) r6[r] = rbf[(size_t)grow * NRR + r];
        #pragma unroll 8
        for (int hh = 0; hh < 64; ++hh) {
            int h = half * 64 + hh;
            float a = b6s[h];
            #pragma unroll
            for (int r = 0; r < NRR; ++r) a += r6[r] * W6[r * HD + h];
            Al[e_l][h] = f2us(siluf(a));
        }
    }
    __syncthreads();

    floatx4 acc[4][4]; ZERO_ACC4(acc);
    store_bh(r0, Bl, tid); __syncthreads();
    mfma_kh(Al, Bl, acc, 0, wr, wc_, lhi, llo);
    __syncthreads();
    store_bh(r1, Bl, tid); __syncthreads();
    mfma_kh(Al, Bl, acc, 1, wr, wc_, lhi, llo);

    #pragma unroll
    for (int tm = 0; tm < 4; ++tm)
        #pragma unroll
        for (int q = 0; q < 4; ++q) {
            int grow = row0 + wr * 64 + tm * 16 + lhi * 4 + q;
            if (grow >= M) continue;
            int zi = z[ii[grow]], zj = z[jj[grow]];
            #pragma unroll
            for (int tn = 0; tn < 4; ++tn) {
                int coll = wc_ * 64 + tn * 16 + llo;
                float t = acc[tm][tn][q] + A0[zi * HD + coll] + A1[zj * HD + coll] + emb_b[coll];
                float v = siluf(t);
                size_t o = (size_t)grow * HD + coll;
                X[o] = v; Xb[o] = f2us(v);
            }
        }
}

// ---------------------------------------------------------------------------
// kjcb: Cb = bf16( silu(x@Wkj+b) * rbfp )   (Wkj in fragment order)
// ---------------------------------------------------------------------------
__global__ __launch_bounds__(256, 3)
void kjcb_w(const ushort_t* __restrict__ Xb, const ushort_t* __restrict__ Wkj,
            const float* __restrict__ bkj, const float* __restrict__ rbf,
            const float* __restrict__ Wr6, ushort_t* __restrict__ Cb, int M)
{
    __shared__ float W6s[NRR * HD];
    __shared__ float bkjS[HD];
    const int tid = threadIdx.x, wave = tid >> 6, lane = tid & 63;
    const int llo = lane & 15, lhi = lane >> 4;
    for (int i = tid; i < NRR * HD; i += 256) W6s[i] = Wr6[i];
    if (tid < HD) bkjS[tid] = bkj[tid];
    __syncthreads();
    const int row0 = (blockIdx.x * 4 + wave) * 16;
    if (row0 >= M) return;

    short8 af[4];
    #pragma unroll
    for (int kc = 0; kc < 4; ++kc)
        af[kc] = *(const short8*)(Xb + (size_t)(row0 + llo) * HD + kc * 32 + lhi * 8);

    short8 nb[2][8];
    #pragma unroll
    for (int d = 0; d < 2; ++d)
        #pragma unroll
        for (int tn = 0; tn < 8; ++tn) nb[d][tn] = ldfrag(Wkj, d * 8 + tn, lane);

    float rb[4][NRR];
    {
        const float* rp = rbf + (size_t)(row0 + lhi * 4) * NRR;
        #pragma unroll
        for (int q = 0; q < 4; ++q)
            #pragma unroll
            for (int r = 0; r < NRR; ++r) rb[q][r] = rp[q * NRR + r];
    }

    floatx4 acc[8]; ZERO_ACC8(acc);
    #pragma unroll
    for (int kc = 0; kc < 4; ++kc) {
        short8 bq[8];
        #pragma unroll
        for (int tn = 0; tn < 8; ++tn) bq[tn] = nb[kc & 1][tn];
        if (kc + 2 < 4) {
            #pragma unroll
            for (int tn = 0; tn < 8; ++tn) nb[kc & 1][tn] = ldfrag(Wkj, (kc + 2) * 8 + tn, lane);
        }
        #pragma unroll
        for (int tn = 0; tn < 8; ++tn)
            acc[tn] = __builtin_amdgcn_mfma_f32_16x16x32_bf16(af[kc], bq[tn], acc[tn], 0, 0, 0);
    }
    #pragma unroll
    for (int tn = 0; tn < 8; ++tn) {
        int col = tn * 16 + llo;
        #pragma unroll
        for (int q = 0; q < 4; ++q) {
            int grow = row0 + lhi * 4 + q;
            if (grow >= M) continue;
            float rpv = 0.f;
            #pragma unroll
            for (int r = 0; r < NRR; ++r) rpv += rb[q][r] * W6s[r * HD + col];
            Cb[(size_t)grow * HD + col] = f2us(siluf(acc[tn][q] + bkjS[col]) * rpv);
        }
    }
}

// ---------------------------------------------------------------------------
// megaK v14 = v13 (measured-best megaK config: 185 us, FETCH 105 MB).
// OCCUPANCY LESSON (R4, R10): (256,5) spilled both times; (256,4) at
// 64 VGPR is the operating point.
// ---------------------------------------------------------------------------
__global__ __launch_bounds__(256, 4)
void megaK_w(const ushort_t* __restrict__ sps, const ushort_t* __restrict__ Cb,
             const int* __restrict__ toffs, const int* __restrict__ ekjs,
             const ushort_t* __restrict__ Xb,
             const ushort_t* __restrict__ Wm,
             const ushort_t* __restrict__ Wji, const float* __restrict__ bjig,
             const ushort_t* __restrict__ Wc, const float* __restrict__ Bc,
             float* __restrict__ X, ushort_t* __restrict__ Xbo)
{
    __shared__ ushort_t Ga[16384];        // 32KB; At/Ct alias the head in phase 0
    const int tid = threadIdx.x, wave = tid >> 6, lane = tid & 63;
    const int llo = lane & 15, lhi = lane >> 4;
    const int tn0 = wave * 2, tn1 = tn0 + 1;
    const int col0 = tn0 * 16 + llo, col1 = tn1 * 16 + llo;

    ushort_t* const At = &Ga[0];          // [128][40] = 5120 ushorts
    ushort_t* const Ct = &Ga[5120];       // [128][40], k-chunk swizzled

    // biases -> registers (loads overlap phase 0)
    const float bj0 = bjig[col0], bj1 = bjig[col1];
    float bsc0[7], bsc1[7];
    #pragma unroll
    for (int s = 0; s < 7; ++s) {
        bsc0[s] = Bc[s * HD + col0];
        bsc1[s] = Bc[s * HD + col1];
    }

    const int row0 = blockIdx.x * 16;

    // ---------- phase 0: gather-GEMM into gacc ----------
    floatx4 gacc[8][2];
    #pragma unroll
    for (int mt = 0; mt < 8; ++mt) {
        gacc[mt][0] = (floatx4){0.f,0.f,0.f,0.f};
        gacc[mt][1] = (floatx4){0.f,0.f,0.f,0.f};
    }
    {
        int tf[17];
        #pragma unroll
        for (int i2 = 0; i2 <= 16; ++i2)
            tf[i2] = __builtin_amdgcn_readfirstlane(toffs[row0 + i2]);
        const int K0 = tf[0], K4 = tf[16];
        const int nch = (K4 - K0 + 31) >> 5;

        const int kk8 = tid >> 3;          // triplet slot 0..31
        const int jsl = tid & 7;           // j slot 0..7
        const int h0  = (tid & 7) * 16;    // h slice for C staging
        const int ksw = (kk8 & 7) | (((kk8 >> 3) ^ (tid & 3)) << 3);
        const int rs0 = (tn0) & 3;
        const int rs1 = (tn1) & 3;

        for (int c = 0; c < nch; ++c) {
            const int kg = K0 + c * 32 + kk8;
            const bool va = kg < K4;

            ushort8v cv0 = {0,0,0,0,0,0,0,0}, cv1 = {0,0,0,0,0,0,0,0};
            ushort_t sv = 0; int eid = 0;
            if (va) {
                const int crow = ekjs[kg];
                cv0 = *(const ushort8v*)(Cb + (size_t)crow * HD + h0);
                cv1 = *(const ushort8v*)(Cb + (size_t)crow * HD + h0 + 8);
                sv  = sps[(size_t)kg * NBB + jsl];
                #pragma unroll
                for (int e2 = 1; e2 <= 16; ++e2) eid += (kg >= tf[e2]) ? 1 : 0;
            }

            {
                unsigned long long* Az = (unsigned long long*)At;
                #pragma unroll
                for (int z = 0; z < 5; ++z) Az[tid * 5 + z] = 0ULL;
            }
            __syncthreads();

            #pragma unroll
            for (int m = 0; m < 8; ++m) {
                Ct[(h0 + m) * 40 + ksw]     = cv0[m];
                Ct[(h0 + 8 + m) * 40 + ksw] = cv1[m];
            }
            if (va) At[(eid * 8 + jsl) * 40 + kk8] = sv;
            __syncthreads();

            {
                short8 bf0 = *(const short8*)&Ct[col0 * 40 + ((lhi ^ rs0) << 3)];
                short8 bf1 = *(const short8*)&Ct[col1 * 40 + ((lhi ^ rs1) << 3)];
                #pragma unroll
                for (int mt = 0; mt < 8; ++mt) {
                    short8 afm = *(const short8*)&At[(mt * 16 + llo) * 40 + lhi * 8];
                    gacc[mt][0] = __builtin_amdgcn_mfma_f32_16x16x32_bf16(afm, bf0, gacc[mt][0], 0, 0, 0);
                    gacc[mt][1] = __builtin_amdgcn_mfma_f32_16x16x32_bf16(afm, bf1, gacc[mt][1], 0, 0, 0);
                }
            }
            __syncthreads();
        }
    }

    // ---------- flush gacc -> Ga (phase-1 A layout, same swizzle) ----------
    #pragma unroll
    for (int mt = 0; mt < 8; ++mt) {
        const int el = mt * 2 + (lhi >> 1);
        const int jb = (lhi & 1) * 4;
        const int sw = (el & 7) << 3;
        #pragma unroll
        for (int nt2 = 0; nt2 < 2; ++nt2) {
            const int h  = wave * 32 + nt2 * 16 + llo;
            const int hx = h ^ sw;
            #pragma unroll
            for (int q = 0; q < 4; ++q)
                Ga[el * 1024 + (jb + q) * 128 + hx] = f2us(gacc[mt][nt2][q]);
        }
    }
    __syncthreads();

    // ---------- phase 1: K=1024 GEMM (A from swizzled LDS) ----------
    floatx4 m0 = {0.f,0.f,0.f,0.f}, m1 = {0.f,0.f,0.f,0.f};
    {
        const int abase = llo << 10;
        const int aswz  = llo & 7;
        short8 ap[2]; short8 bp[4][2];
        #pragma unroll
        for (int d = 0; d < 2; ++d)
            ap[d] = *(const short8*)&Ga[abase + ((((d << 2) + lhi) ^ aswz) << 3)];
        #pragma unroll
        for (int d = 0; d < 4; ++d) {
            bp[d][0] = ldfrag(Wm, d * 8 + tn0, lane);
            bp[d][1] = ldfrag(Wm, d * 8 + tn1, lane);
        }
        __builtin_amdgcn_s_setprio(1);
        #pragma unroll
        for (int kc = 0; kc < 32; ++kc) {
            short8 a  = ap[kc & 1];
            short8 b0 = bp[kc & 3][0], b1 = bp[kc & 3][1];
            if (kc + 2 < 32)
                ap[kc & 1] = *(const short8*)&Ga[abase + (((((kc + 2) << 2) + lhi) ^ aswz) << 3)];
            if (kc + 4 < 32) {
                bp[kc & 3][0] = ldfrag(Wm, (kc + 4) * 8 + tn0, lane);
                bp[kc & 3][1] = ldfrag(Wm, (kc + 4) * 8 + tn1, lane);
            }
            m0 = __builtin_amdgcn_mfma_f32_16x16x32_bf16(a, b0, m0, 0, 0, 0);
            m1 = __builtin_amdgcn_mfma_f32_16x16x32_bf16(a, b1, m1, 0, 0, 0);
        }
        __builtin_amdgcn_s_setprio(0);
    }
    __syncthreads();   // Ga is dead past here; Tw (alias) becomes live

    ushort_t (*Tw)[136] = (ushort_t (*)[136])&Ga[0];

    // ---------- phase 2: x_ji GEMM; hin = silu(.)+m kept in registers ----------
    float cur0[4], cur1[4], res0[4], res1[4], trk0[4], trk1[4];
    short8 nb[2][2];
    #pragma unroll
    for (int d = 0; d < 2; ++d) {
        nb[d][0] = ldfrag(Wji, d * 8 + tn0, lane);
        nb[d][1] = ldfrag(Wji, d * 8 + tn1, lane);
    }
    {
        short8 af[4];
        #pragma unroll
        for (int kc = 0; kc < 4; ++kc)
            af[kc] = *(const short8*)(Xb + (size_t)(row0 + llo) * HD + kc * 32 + lhi * 8);
        floatx4 a0 = {0.f,0.f,0.f,0.f}, a1 = {0.f,0.f,0.f,0.f};
        #pragma unroll
        for (int kc = 0; kc < 4; ++kc) {
            short8 b0 = nb[kc & 1][0], b1 = nb[kc & 1][1];
            {   // prefetch seg kc+2 (crosses into chain stage 0 weights)
                const int ps = kc + 2;
                const ushort_t* W = (ps < 4) ? Wji : Wc;
                nb[kc & 1][0] = ldfrag(W, (ps & 3) * 8 + tn0, lane);
                nb[kc & 1][1] = ldfrag(W, (ps & 3) * 8 + tn1, lane);
            }
            a0 = __builtin_amdgcn_mfma_f32_16x16x32_bf16(af[kc], b0, a0, 0, 0, 0);
            a1 = __builtin_amdgcn_mfma_f32_16x16x32_bf16(af[kc], b1, a1, 0, 0, 0);
        }
        #pragma unroll
        for (int q = 0; q < 4; ++q) {
            res0[q] = siluf(a0[q] + bj0) + m0[q];
            res1[q] = siluf(a1[q] + bj1) + m1[q];
            cur0[q] = res0[q]; cur1[q] = res1[q];
        }
    }

    // prefetch X residual (consumed at chain stage s==2)
    float xr0[4], xr1[4];
    #pragma unroll
    for (int q = 0; q < 4; ++q) {
        int grow = row0 + lhi * 4 + q;
        xr0[q] = X[(size_t)grow * HD + col0];
        xr1[q] = X[(size_t)grow * HD + col1];
    }

    // ---------- chain stages (7) ----------
    #pragma unroll
    for (int s = 0; s < 7; ++s) {
        #pragma unroll
        for (int q = 0; q < 4; ++q) {
            Tw[lhi * 4 + q][col0] = f2us(cur0[q]);
            Tw[lhi * 4 + q][col1] = f2us(cur1[q]);
        }
        __syncthreads();

        floatx4 a0 = {0.f,0.f,0.f,0.f}, a1 = {0.f,0.f,0.f,0.f};
        const int sg0 = 4 + s * 4;
        #pragma unroll
        for (int kc = 0; kc < 4; ++kc) {
            const int seg = sg0 + kc;
            short8 a8 = *(const short8*)&Tw[llo][kc * 32 + lhi * 8];
            short8 b0 = nb[seg & 1][0], b1 = nb[seg & 1][1];
            if (seg + 2 < 32) {
                const int ps = seg + 2;
                const ushort_t* W = Wc + (size_t)((ps - 4) >> 2) * MSZ;
                nb[seg & 1][0] = ldfrag(W, (ps & 3) * 8 + tn0, lane);
                nb[seg & 1][1] = ldfrag(W, (ps & 3) * 8 + tn1, lane);
            }
            a0 = __builtin_amdgcn_mfma_f32_16x16x32_bf16(a8, b0, a0, 0, 0, 0);
            a1 = __builtin_amdgcn_mfma_f32_16x16x32_bf16(a8, b1, a1, 0, 0, 0);
        }
        __syncthreads();

        #pragma unroll
        for (int q = 0; q < 4; ++q) {
            float t0v = siluf(a0[q] + bsc0[s]);
            float t1v = siluf(a1[q] + bsc1[s]);
            if (s == 0)      { cur0[q] = t0v; cur1[q] = t1v; }
            else if (s == 1) { cur0[q] = t0v + res0[q]; cur1[q] = t1v + res1[q]; }
            else if (s == 2) {
                cur0[q] = t0v + xr0[q];
                cur1[q] = t1v + xr1[q];
                trk0[q] = cur0[q]; trk1[q] = cur1[q];
            }
            else if (s == 3 || s == 5) { cur0[q] = t0v; cur1[q] = t1v; }
            else {
                cur0[q] = t0v + trk0[q]; cur1[q] = t1v + trk1[q];
                trk0[q] = cur0[q]; trk1[q] = cur1[q];
            }
        }
    }

    #pragma unroll
    for (int q = 0; q < 4; ++q) {
        int grow = row0 + lhi * 4 + q;
        size_t o = (size_t)grow * HD;
        X[o + col0] = cur0[q];        X[o + col1] = cur1[q];
        Xbo[o + col0] = f2us(cur0[q]); Xbo[o + col1] = f2us(cur1[q]);
    }
}

// ---------------------------------------------------------------------------
// gatherT v2: ring-pipelined CSR gather (R3 recipe).
// ---------------------------------------------------------------------------
__global__ __launch_bounds__(256)
void gatherT_k(const ushort_t* __restrict__ Xb, const float* __restrict__ rbf,
               const float* __restrict__ Wr6, const int* __restrict__ eoffs,
               const int* __restrict__ esorted, ushort_t* __restrict__ TA, int M)
{
    __shared__ float W6s[NRR * HD];
    const int tid = threadIdx.x, wave = tid >> 6, lane = tid & 63;
    for (int i = tid; i < NRR * HD; i += 256) W6s[i] = Wr6[i];
    __syncthreads();

    const int c0 = lane * 2;
    float w0[NRR], w1[NRR];
    #pragma unroll
    for (int r = 0; r < NRR; ++r) {
        w0[r] = W6s[r * HD + c0];
        w1[r] = W6s[r * HD + c0 + 1];
    }
    const uint_t* __restrict__ Xb32 = (const uint_t*)Xb;

    int a0 = (blockIdx.x * 4 + wave) * 2;
    #pragma unroll 1
    for (int s = 0; s < 2; ++s) {
        int a = a0 + s;
        if (a >= M) return;
        float acc0 = 0.f, acc1 = 0.f;
        const int k0 = __builtin_amdgcn_readfirstlane(eoffs[a]);
        const int k1 = __builtin_amdgcn_readfirstlane(eoffs[a + 1]);

        uint_t xv[4]; float rb[4][NRR];
        #pragma unroll
        for (int p = 0; p < 4; ++p)
            if (k0 + p < k1) {
                const int e = __builtin_amdgcn_readfirstlane(esorted[k0 + p]);
                xv[p] = Xb32[(size_t)e * 64 + lane];
                #pragma unroll
                for (int r = 0; r < NRR; ++r) rb[p][r] = rbf[(size_t)e * NRR + r];
            }

        for (int base = k0; base < k1; base += 4) {
            #pragma unroll
            for (int p = 0; p < 4; ++p) {
                const int k = base + p;
                if (k < k1) {
                    const uint_t xc = xv[p];
                    float rp0 = 0.f, rp1 = 0.f;
                    #pragma unroll
                    for (int r = 0; r < NRR; ++r) {
                        rp0 += rb[p][r] * w0[r];
                        rp1 += rb[p][r] * w1[r];
                    }
                    if (k + 4 < k1) {
                        const int en = __builtin_amdgcn_readfirstlane(esorted[k + 4]);
                        xv[p] = Xb32[(size_t)en * 64 + lane];
                        #pragma unroll
                        for (int r = 0; r < NRR; ++r) rb[p][r] = rbf[(size_t)en * NRR + r];
                    }
                    acc0 += rp0 * us2f((ushort_t)(xc & 0xffffu));
                    acc1 += rp1 * __builtin_bit_cast(float, xc & 0xffff0000u);
                }
            }
        }
        TA[(size_t)a * HD + c0]     = f2us(acc0);
        TA[(size_t)a * HD + c0 + 1] = f2us(acc1);
    }
}

__global__ __launch_bounds__(256, 3)
void atomchain_w(const ushort_t* __restrict__ TA, const ushort_t* __restrict__ Wl,
                 const float* __restrict__ bl, const float* __restrict__ wout,
                 float* __restrict__ P, int M)
{
    __shared__ float blS[3 * HD];
    __shared__ float woS[HD];
    __shared__ ushort_t T[4][16][136];
    const int tid = threadIdx.x, wave = tid >> 6, lane = tid & 63;
    const int llo = lane & 15, lhi = lane >> 4;
    for (int i = tid; i < 3 * HD; i += 256) blS[i] = bl[i];
    if (tid < HD) woS[tid] = wout[tid];
    __syncthreads();
    const int row0 = (blockIdx.x * 4 + wave) * 16;
    if (row0 >= M) return;
    ushort_t (*Tw)[136] = T[wave];

    short8 nb[2][8];
    #pragma unroll
    for (int d = 0; d < 2; ++d)
        #pragma unroll
        for (int tn = 0; tn < 8; ++tn) nb[d][tn] = ldfrag(Wl, d * 8 + tn, lane);

    #pragma unroll
    for (int s = 0; s < 3; ++s) {
        short8 af[4];
        if (s == 0) {
            #pragma unroll
            for (int kc = 0; kc < 4; ++kc)
                af[kc] = *(const short8*)(TA + (size_t)(row0 + llo) * HD + kc * 32 + lhi * 8);
        } else {
            #pragma unroll
            for (int kc = 0; kc < 4; ++kc)
                af[kc] = *(const short8*)&Tw[llo][kc * 32 + lhi * 8];
        }
        floatx4 acc[8]; ZERO_ACC8(acc);
        #pragma unroll
        for (int kc = 0; kc < 4; ++kc) {
            const int seg = s * 4 + kc;
            short8 bq[8];
            #pragma unroll
            for (int tn = 0; tn < 8; ++tn) bq[tn] = nb[seg & 1][tn];
            if (seg + 2 < 12) {
                const int ps = seg + 2;
                const ushort_t* W = Wl + (size_t)(ps >> 2) * MSZ;
                #pragma unroll
                for (int tn = 0; tn < 8; ++tn)
                    nb[seg & 1][tn] = ldfrag(W, (ps & 3) * 8 + tn, lane);
            }
            #pragma unroll
            for (int tn = 0; tn < 8; ++tn)
                acc[tn] = __builtin_amdgcn_mfma_f32_16x16x32_bf16(af[kc], bq[tn], acc[tn], 0, 0, 0);
        }
        if (s < 2) {
            wave_lds_fence();
            #pragma unroll
            for (int tn = 0; tn < 8; ++tn) {
                int col = tn * 16 + llo;
                #pragma unroll
                for (int q = 0; q < 4; ++q)
                    Tw[lhi * 4 + q][col] = f2us(siluf(acc[tn][q] + blS[s * HD + col]));
            }
            wave_lds_fence();
        } else {
            #pragma unroll
            for (int q = 0; q < 4; ++q) {
                float v = 0.f;
                #pragma unroll
                for (int tn = 0; tn < 8; ++tn) {
                    int col = tn * 16 + llo;
                    v += siluf(acc[tn][q] + blS[2 * HD + col]) * woS[col];
                }
                v += __shfl_xor(v, 1); v += __shfl_xor(v, 2);
                v += __shfl_xor(v, 4); v += __shfl_xor(v, 8);
                int a = row0 + lhi * 4 + q;
                if (llo == 0 && a < M) P[a] += v;
            }
        }
    }
}

// ---------------- small kernels ----------------
__global__ void emb_lin_k(const float* __restrict__ emb_table, const float* __restrict__ emb_w,
                          float* __restrict__ A0, float* __restrict__ A1)
{
    __shared__ float er[HD];
    int a = blockIdx.x, h = threadIdx.x;
    er[h] = emb_table[a * HD + h];
    __syncthreads();
    float acc0 = 0.f, acc1 = 0.f;
    #pragma unroll 8
    for (int l = 0; l < HD; ++l) {
        float e = er[l];
        acc0 += e * emb_w[l * HD + h];
        acc1 += e * emb_w[(HD + l) * HD + h];
    }
    A0[a * HD + h] = acc0;
    A1[a * HD + h] = acc1;
}

// ---------------------------------------------------------------------------
// sbf_proj6 v3: iterate over SORTED positions. Thread p gather-reads
// sbf[tsorted[p]] (scattered 168 B rows, ~1.4x read amplification, no RMW)
// and writes all nw planes COALESCED at sps6[b*plane + p*8] (lane-contiguous
// 16 B x 64 = 1 KB wave stores). R13's tpos-scattered 6x16B writes caused
// ~4x RMW write amplification; this moves the scatter to the read side.
// Numerics identical (same dot products / rounding; only thread mapping).
// ---------------------------------------------------------------------------
__global__ void sbf_proj6_k(const float* __restrict__ sbf, const float* __restrict__ W,
                            const int* __restrict__ tsorted, ushort_t* __restrict__ sps6,
                            int nw, size_t plane)
{
    __shared__ float Ws[NBLKS * NSNR * NBB];
    for (int s = threadIdx.x; s < nw * NSNR * NBB; s += 256) Ws[s] = W[s];
    __syncthreads();
    int p = blockIdx.x * 256 + threadIdx.x;
    if (p >= NTRIP) return;
    const int t = tsorted[p];
    float sv[NSNR];
    #pragma unroll
    for (int r = 0; r < NSNR; ++r) sv[r] = sbf[(size_t)t * NSNR + r];
    for (int b = 0; b < nw; ++b) {
        float acc[NBB];
        #pragma unroll
        for (int n = 0; n < NBB; ++n) acc[n] = 0.f;
        const float* Wb = &Ws[b * NSNR * NBB];
        #pragma unroll
        for (int r = 0; r < NSNR; ++r) {
            float v = sv[r];
            #pragma unroll
            for (int n = 0; n < NBB; ++n) acc[n] += v * Wb[r * NBB + n];
        }
        ushort8v pk;
        #pragma unroll
        for (int n = 0; n < NBB; ++n) pk[n] = f2us(acc[n]);
        *(ushort8v*)(sps6 + (size_t)b * plane + (size_t)p * NBB) = pk;
    }
}

__global__ void graph_sum_k(const float* __restrict__ P, const int* __restrict__ batch,
                            float* __restrict__ outg)
{
    int a = blockIdx.x * 256 + threadIdx.x;
    if (a >= NATOMS) return;
    atomicAdd(&outg[batch[a]], P[a]);
}

// ---------------------------------------------------------------------------
extern "C" void kernel_launch(void* const* d_in, const int* in_sizes, int n_in,
                              void* d_out, int out_size, void* d_ws, size_t ws_size,
                              hipStream_t stream)
{
    const int*   z         = (const int*)  d_in[0];
    const float* rbf       = (const float*)d_in[1];
    const float* sbf       = (const float*)d_in[2];
    const int*   ii        = (const int*)  d_in[3];
    const int*   jj        = (const int*)  d_in[4];
    const int*   idx_kj    = (const int*)  d_in[5];
    const int*   idx_ji    = (const int*)  d_in[6];
    const int*   batch     = (const int*)  d_in[7];
    const float* emb_table = (const float*)d_in[8];
    const float* emb_rbf_w = (const float*)d_in[9];
    const float* emb_rbf_b = (const float*)d_in[10];
    const float* emb_w     = (const float*)d_in[11];
    const float* emb_b     = (const float*)d_in[12];
    const float* int_rbf_w = (const float*)d_in[13];
    const float* int_sbf_w = (const float*)d_in[14];
    const float* int_kj_w  = (const float*)d_in[15];
    const float* int_kj_b  = (const float*)d_in[16];
    const float* int_ji_w  = (const float*)d_in[17];
    const float* int_ji_b  = (const float*)d_in[18];
    const float* int_W     = (const float*)d_in[19];
    const float* int_bef_w = (const float*)d_in[20];
    const float* int_bef_b = (const float*)d_in[21];
    const float* int_lin_w = (const float*)d_in[22];
    const float* int_lin_b = (const float*)d_in[23];
    const float* int_aft_w = (const float*)d_in[24];
    const float* int_aft_b = (const float*)d_in[25];
    const float* out_rbf_w = (const float*)d_in[26];
    const float* out_lins_w= (const float*)d_in[27];
    const float* out_lins_b= (const float*)d_in[28];
    const float* out_w     = (const float*)d_in[29];
    float* d_outf          = (float*)d_out;

    const size_t EH = (size_t)NEDGES * HD;
    const int OFF_EMB = 0, OFF_KJ = 1, OFF_JI = 7, OFF_CHAIN = 13, OFF_OUTL = 55;

    char* base = (char*)d_ws;
    auto take = [&](size_t bytes) { char* p = base; base += (bytes + 255) & ~(size_t)255; return p; };
    float* bufA    = (float*)take(EH * 4);
    ushort_t* Xb   = (ushort_t*)take(EH * 2);
    ushort_t* Cb   = (ushort_t*)take(EH * 2);
    ushort_t* TA   = (ushort_t*)take((size_t)NATOMS * HD * 2);
    float* P_atom  = (float*)take((size_t)NATOMS * 4);
    float* A0      = (float*)take(95 * HD * 4);
    float* A1      = (float*)take(95 * HD * 4);
    float* bc      = (float*)take((size_t)NBLKS * 7 * HD * 4);
    int*   counts  = (int*)  take((size_t)(NEDGES + 1) * 4);
    int*   bsum    = (int*)  take(1024 * 4);
    int*   toffs   = (int*)  take((size_t)(NEDGES + 1) * 4);
    int*   eoffs   = (int*)  take((size_t)(NATOMS + 1) * 4);
    int*   tsorted = (int*)  take((size_t)NTRIP * 4);
    int*   esorted = (int*)  take((size_t)NEDGES * 4);
    int*   tpos    = (int*)  take((size_t)NTRIP * 4);
    int*   ekjs    = (int*)  take((size_t)NTRIP * 4);
    ushort_t* w128 = (ushort_t*)take((size_t)76 * MSZ * 2);
    ushort_t* wM   = (ushort_t*)take((size_t)NBLKS * HD * 1024 * 2);

    // sps allocated last, fused 6-plane (plane-major) if workspace allows
    size_t used = (size_t)(base - (char*)d_ws);
    size_t need6 = (size_t)NTRIP * NBLKS * NBB * 2;
    int nw = (used + need6 + 256 <= ws_size) ? NBLKS : 1;
    ushort_t* sps = (ushort_t*)take((size_t)NTRIP * nw * NBB * 2);
    const size_t plane = (size_t)NTRIP * NBB;

    auto zero = [&](float* p, size_t n) {
        zerof_k<<<((int)n + 255) / 256, 256, 0, stream>>>(p, (int)n);
    };

    // ---------------- weight prep ----------------
    transp128_k<<< 1, 256, 0, stream>>>(emb_w + 2 * MSZ, w128 + (size_t)OFF_EMB * MSZ);
    transp128s_k<<< 6, 256, 0, stream>>>(int_kj_w,   w128 + (size_t)OFF_KJ  * MSZ);
    transp128s_k<<< 6, 256, 0, stream>>>(int_ji_w,   w128 + (size_t)OFF_JI  * MSZ);
    for (int b = 0; b < NBLKS; ++b) {
        transp128s_k<<<2, 256, 0, stream>>>(int_bef_w + (size_t)b * 2 * MSZ,
                                            w128 + (size_t)(OFF_CHAIN + b * 7) * MSZ);
        transp128s_k<<<1, 256, 0, stream>>>(int_lin_w + (size_t)b * MSZ,
                                            w128 + (size_t)(OFF_CHAIN + b * 7 + 2) * MSZ);
        transp128s_k<<<4, 256, 0, stream>>>(int_aft_w + (size_t)b * 4 * MSZ,
                                            w128 + (size_t)(OFF_CHAIN + b * 7 + 3) * MSZ);
    }
    transp128s_k<<<21, 256, 0, stream>>>(out_lins_w, w128 + (size_t)OFF_OUTL * MSZ);
    castWMs_k<<<(NBLKS * HD * 1024 + 255) / 256, 256, 0, stream>>>(int_W, wM, NBLKS * HD * 1024);
    pack_bc_k<<<NBLKS, 256, 0, stream>>>(int_bef_b, int_lin_b, int_aft_b, bc);

    // ---------------- CSR builds ----------------
    {
        zeroi_k<<<(NEDGES + 255) / 256, 256, 0, stream>>>(counts, NEDGES);
        hist_k<<<(NTRIP + 255) / 256, 256, 0, stream>>>(idx_ji, NTRIP, counts);
        int nb = (NEDGES + 255) / 256;
        blksum_k<<<nb, 256, 0, stream>>>(counts, NEDGES, bsum);
        scanb_k<<<1, 1024, 0, stream>>>(bsum, nb);
        scanfin_k<<<nb, 256, 0, stream>>>(counts, NEDGES, bsum, toffs);
        zeroi_k<<<(NEDGES + 255) / 256, 256, 0, stream>>>(counts, NEDGES);
        fill_k<<<(NTRIP + 255) / 256, 256, 0, stream>>>(idx_ji, NTRIP, toffs, counts, tsorted);
        invperm_k<<<(NTRIP + 255) / 256, 256, 0, stream>>>(tsorted, idx_kj, tpos, ekjs, NTRIP);
    }
    {
        zeroi_k<<<(NATOMS + 255) / 256, 256, 0, stream>>>(counts, NATOMS);
        hist_k<<<(NEDGES + 255) / 256, 256, 0, stream>>>(ii, NEDGES, counts);
        int nb = (NATOMS + 255) / 256;
        blksum_k<<<nb, 256, 0, stream>>>(counts, NATOMS, bsum);
        scanb_k<<<1, 1024, 0, stream>>>(bsum, nb);
        scanfin_k<<<nb, 256, 0, stream>>>(counts, NATOMS, bsum, eoffs);
        zeroi_k<<<(NATOMS + 255) / 256, 256, 0, stream>>>(counts, NATOMS);
        fill_k<<<(NEDGES + 255) / 256, 256, 0, stream>>>(ii, NEDGES, eoffs, counts, esorted);
    }

    const int EGRID = (NEDGES + 127) / 128;
    const int EW    = (NEDGES / 16 + 3) / 4;
    const int AW    = (NATOMS / 16 + 3) / 4;
    const int GW    = (NATOMS / 2 + 3) / 4;
    const int MW    = NEDGES / 16;   // 6250, exact
    auto out_block = [&](int k) {
        gatherT_k<<<GW, 256, 0, stream>>>(
            Xb, rbf, out_rbf_w + (size_t)k * NRR * HD, eoffs, esorted, TA, NATOMS);
        atomchain_w<<<AW, 256, 0, stream>>>(
            TA, w128 + (size_t)(OFF_OUTL + 3 * k) * MSZ,
            out_lins_b + (size_t)k * 3 * HD, out_w + (size_t)k * HD, P_atom, NATOMS);
    };

    // ---------------- Embedding ----------------
    emb_lin_k<<<95, HD, 0, stream>>>(emb_table, emb_w, A0, A1);
    emb_chain_k<<<EGRID, 256, 0, stream>>>(
        rbf, emb_rbf_w, emb_rbf_b, w128 + (size_t)OFF_EMB * MSZ,
        A0, A1, emb_b, z, ii, jj, bufA, Xb, NEDGES);

    zero(P_atom, NATOMS);
    out_block(0);

    // fused sbf projection (one pass over sbf for all 6 blocks, plane-major,
    // sorted-position order -> coalesced writes)
    if (nw == NBLKS)
        sbf_proj6_k<<<(NTRIP + 255) / 256, 256, 0, stream>>>(
            sbf, int_sbf_w, tsorted, sps, NBLKS, plane);

    // ---------------- Interaction blocks ----------------
    for (int b = 0; b < NBLKS; ++b) {
        if (nw != NBLKS)
            sbf_proj6_k<<<(NTRIP + 255) / 256, 256, 0, stream>>>(
                sbf, int_sbf_w + (size_t)b * NSNR * NBB, tsorted, sps, 1, plane);

        kjcb_w<<<EW, 256, 0, stream>>>(
            Xb, w128 + (size_t)(OFF_KJ + b) * MSZ, int_kj_b + (size_t)b * HD,
            rbf, int_rbf_w + (size_t)b * NRR * HD, Cb, NEDGES);

        megaK_w<<<MW, 256, 0, stream>>>(
            sps + (nw == NBLKS ? (size_t)b * plane : 0), Cb, toffs, ekjs, Xb,
            wM + (size_t)b * HD * 1024,
            w128 + (size_t)(OFF_JI + b) * MSZ, int_ji_b + (size_t)b * HD,
            w128 + (size_t)(OFF_CHAIN + b * 7) * MSZ, bc + (size_t)b * 7 * HD,
            bufA, Xb);

        out_block(b + 1);
    }

    // ---------------- Final graph reduction ----------------
    zero(d_outf, NGRAPH);
    graph_sum_k<<<(NATOMS + 255) / 256, 256, 0, stream>>>(P_atom, batch, d_outf);
}

// Round 15
// 1893.985 us; speedup vs baseline: 1.0619x; 1.0619x over previous
//
#include <hip/hip_runtime.h>
#include <cstdint>
#include <cstddef>

typedef unsigned short ushort_t;
typedef unsigned int uint_t;

#define NATOMS 8000
#define NEDGES 100000
#define NTRIP  500000
#define NGRAPH 64
#define HD     128
#define NRR    6
#define NSNR   42
#define NBB    8
#define NBLKS  6
#define MSZ    16384

using short8   = __attribute__((ext_vector_type(8))) short;
using ushort8v = __attribute__((ext_vector_type(8))) unsigned short;
using floatx4  = __attribute__((ext_vector_type(4))) float;
using float2v  = __attribute__((ext_vector_type(2))) float;

__device__ __forceinline__ float siluf(float x){ return x / (1.f + __expf(-x)); }
__device__ __forceinline__ ushort_t f2us(float f){
    uint_t u = __builtin_bit_cast(uint_t, f);
    u = (u + 0x7FFFu + ((u >> 16) & 1u)) >> 16;
    return (ushort_t)u;
}
__device__ __forceinline__ float us2f(ushort_t s){
    uint_t u = ((uint_t)s) << 16;
    return __builtin_bit_cast(float, u);
}
__device__ __forceinline__ void wave_lds_fence(){
    asm volatile("s_waitcnt lgkmcnt(0)" ::: "memory");
}
__device__ __forceinline__ short8 ldfrag(const ushort_t* W, int frag, int lane){
    return *(const short8*)(W + ((size_t)(frag * 64 + lane) << 3));
}

__global__ void zerof_k(float* __restrict__ p, int n){ int i=blockIdx.x*256+threadIdx.x; if(i<n) p[i]=0.f; }
__global__ void zeroi_k(int* __restrict__ p, int n){ int i=blockIdx.x*256+threadIdx.x; if(i<n) p[i]=0; }

// ---------------- weight prep ----------------
__global__ __launch_bounds__(256)
void transp128_k(const float* __restrict__ src, ushort_t* __restrict__ dst)
{
    __shared__ ushort_t L[128][130];
    int m = blockIdx.x;
    const float* S = src + (size_t)m * MSZ;
    ushort_t* D = dst + (size_t)m * MSZ;
    int tid = threadIdx.x;
    #pragma unroll
    for (int p = 0; p < 64; ++p) {
        int idx = p * 256 + tid;
        int k = idx >> 7, n = idx & 127;
        L[k][n] = f2us(S[idx]);
    }
    __syncthreads();
    #pragma unroll
    for (int p = 0; p < 64; ++p) {
        int idx = p * 256 + tid;
        int n = idx >> 7, k = idx & 127;
        D[idx] = L[k][n];
    }
}

// fragment order (K=128)
__global__ __launch_bounds__(256)
void transp128s_k(const float* __restrict__ src, ushort_t* __restrict__ dst)
{
    int m = blockIdx.x;
    const float* S = src + (size_t)m * MSZ;
    ushort_t* D = dst + (size_t)m * MSZ;
    int tid = threadIdx.x;
    #pragma unroll
    for (int p = 0; p < 64; ++p) {
        int idx = p * 256 + tid;
        int k = idx >> 7, n = idx & 127;
        size_t d = ((size_t)(((k >> 5) * 8 + (n >> 4)) * 64 + ((k >> 3) & 3) * 16 + (n & 15)) << 3)
                   + (k & 7);
        D[d] = f2us(S[idx]);
    }
}

// int_W -> fragment order (K=1024)
__global__ void castWMs_k(const float* __restrict__ src, ushort_t* __restrict__ dst, int n)
{
    int i = blockIdx.x * 256 + threadIdx.x;
    if (i >= n) return;
    int b = i >> 17;
    int r = i & 131071;
    int nn = r >> 10, k = r & 1023;
    size_t d = (size_t)b * 131072
             + ((size_t)(((k >> 5) * 8 + (nn >> 4)) * 64 + ((k >> 3) & 3) * 16 + (nn & 15)) << 3)
             + (k & 7);
    dst[d] = f2us(src[i]);
}

__global__ void pack_bc_k(const float* __restrict__ bef, const float* __restrict__ lin,
                          const float* __restrict__ aft, float* __restrict__ bc)
{
    int b = blockIdx.x;
    for (int i = threadIdx.x; i < 7 * HD; i += 256) {
        int s = i >> 7, h = i & 127;
        float v;
        if (s < 2)      v = bef[(size_t)(b * 2 + s) * HD + h];
        else if (s == 2) v = lin[(size_t)b * HD + h];
        else             v = aft[(size_t)(b * 4 + (s - 3)) * HD + h];
        bc[(size_t)b * 7 * HD + i] = v;
    }
}

// ---------------- CSR build ----------------
__global__ void hist_k(const int* __restrict__ idx, int n, int* __restrict__ cnt)
{
    int i = blockIdx.x * 256 + threadIdx.x;
    if (i < n) atomicAdd(&cnt[idx[i]], 1);
}
__global__ void blksum_k(const int* __restrict__ c, int n, int* __restrict__ bs)
{
    int i = blockIdx.x * 256 + threadIdx.x;
    int v = (i < n) ? c[i] : 0;
    #pragma unroll
    for (int off = 32; off; off >>= 1) v += __shfl_down(v, off);
    __shared__ int sh[4];
    if ((threadIdx.x & 63) == 0) sh[threadIdx.x >> 6] = v;
    __syncthreads();
    if (threadIdx.x == 0) bs[blockIdx.x] = sh[0] + sh[1] + sh[2] + sh[3];
}
__global__ void scanb_k(int* __restrict__ bs, int nb)
{
    __shared__ int sh[1024];
    int t = threadIdx.x;
    int v = (t < nb) ? bs[t] : 0;
    sh[t] = v; __syncthreads();
    for (int off = 1; off < 1024; off <<= 1) {
        int u = (t >= off) ? sh[t - off] : 0;
        __syncthreads();
        sh[t] += u;
        __syncthreads();
    }
    if (t < nb) bs[t] = sh[t] - v;
}
__global__ void scanfin_k(const int* __restrict__ c, int n, const int* __restrict__ bs,
                          int* __restrict__ offs)
{
    __shared__ int sh[256];
    int t = threadIdx.x;
    int i = blockIdx.x * 256 + t;
    int v = (i < n) ? c[i] : 0;
    sh[t] = v; __syncthreads();
    for (int off = 1; off < 256; off <<= 1) {
        int u = (t >= off) ? sh[t - off] : 0;
        __syncthreads();
        sh[t] += u;
        __syncthreads();
    }
    if (i < n)  offs[i] = bs[blockIdx.x] + sh[t] - v;
    if (i == n - 1) offs[n] = bs[blockIdx.x] + sh[t];
}
__global__ void fill_k(const int* __restrict__ idx, int n, const int* __restrict__ offs,
                       int* __restrict__ cur, int* __restrict__ sorted)
{
    int i = blockIdx.x * 256 + threadIdx.x;
    if (i >= n) return;
    int e = idx[i];
    int p = offs[e] + atomicAdd(&cur[e], 1);
    sorted[p] = i;
}
__global__ void invperm_k(const int* __restrict__ tsorted, const int* __restrict__ idx_kj,
                          int* __restrict__ tpos, int* __restrict__ ekjs, int n)
{
    int k = blockIdx.x * 256 + threadIdx.x;
    if (k >= n) return;
    int t = tsorted[k];
    tpos[t] = k;
    ekjs[k] = idx_kj[t];
}

// ---------------------------------------------------------------------------
// Legacy block helpers (emb_chain only)
// ---------------------------------------------------------------------------
__device__ __forceinline__ void load_bh(const ushort_t* Bt, int kh, int tid, ushort8v r[4])
{
    #pragma unroll
    for (int p = 0; p < 4; ++p) {
        int c = p * 256 + tid;
        int n = c >> 3, c8 = c & 7;
        r[p] = *(const ushort8v*)(Bt + (size_t)n * 128 + kh * 64 + c8 * 8);
    }
}
__device__ __forceinline__ void store_bh(ushort8v r[4], ushort_t (*Bl)[72], int tid)
{
    #pragma unroll
    for (int p = 0; p < 4; ++p) {
        int c = p * 256 + tid;
        *(ushort8v*)&Bl[c >> 3][(c & 7) * 8] = r[p];
    }
}
__device__ __forceinline__ void mfma_kh(ushort_t (*Al)[136], ushort_t (*Bl)[72],
                                        floatx4 acc[4][4], int kh,
                                        int wr, int wc, int lhi, int llo)
{
    #pragma unroll
    for (int ks = 0; ks < 2; ++ks) {
        int kk = ks * 32 + lhi * 8;
        short8 af[4], bf[4];
        #pragma unroll
        for (int tm = 0; tm < 4; ++tm)
            af[tm] = *(const short8*)&Al[wr * 64 + tm * 16 + llo][kh * 64 + kk];
        #pragma unroll
        for (int tn = 0; tn < 4; ++tn)
            bf[tn] = *(const short8*)&Bl[wc * 64 + tn * 16 + llo][kk];
        #pragma unroll
        for (int tm = 0; tm < 4; ++tm)
            #pragma unroll
            for (int tn = 0; tn < 4; ++tn)
                acc[tm][tn] = __builtin_amdgcn_mfma_f32_16x16x32_bf16(
                    af[tm], bf[tn], acc[tm][tn], 0, 0, 0);
    }
}
#define ZERO_ACC4(acc) { _Pragma("unroll") for (int a_=0;a_<4;++a_) _Pragma("unroll") \
    for (int b_=0;b_<4;++b_) _Pragma("unroll") for (int q_=0;q_<4;++q_) acc[a_][b_][q_]=0.f; }
#define ZERO_ACC8(acc) { _Pragma("unroll") for (int t_=0;t_<8;++t_) { acc[t_][0]=0.f; acc[t_][1]=0.f; acc[t_][2]=0.f; acc[t_][3]=0.f; } }

// ---------------------------------------------------------------------------
// Embedding chain (block-tiled, classic weight layout)
// R15: X f32 output dropped — the only consumer was megaK's s==2 residual,
// which now reads Xb (bf16). Saves 51 MB of write traffic.
// ---------------------------------------------------------------------------
__global__ __launch_bounds__(256)
void emb_chain_k(const float* __restrict__ rbf, const float* __restrict__ W6g,
                 const float* __restrict__ b6g, const ushort_t* __restrict__ Wemb3,
                 const float* __restrict__ A0, const float* __restrict__ A1,
                 const float* __restrict__ emb_b, const int* __restrict__ z,
                 const int* __restrict__ ii, const int* __restrict__ jj,
                 ushort_t* __restrict__ Xb, int M)
{
    __shared__ ushort_t Al[128][136];
    __shared__ ushort_t Bl[128][72];
    __shared__ float W6[NRR * HD];
    __shared__ float b6s[HD];
    const int tid = threadIdx.x, row0 = blockIdx.x * 128;
    const int wave = tid >> 6, lane = tid & 63;
    const int wr = wave >> 1, wc_ = wave & 1, lhi = lane >> 4, llo = lane & 15;

    for (int i = tid; i < NRR * HD; i += 256) W6[i] = W6g[i];
    if (tid < HD) b6s[tid] = b6g[tid];
    ushort8v r0[4], r1[4];
    load_bh(Wemb3, 0, tid, r0); load_bh(Wemb3, 1, tid, r1);
    __syncthreads();

    {
        int e_l = tid >> 1, half = tid & 1;
        int grow = row0 + e_l; if (grow >= M) grow = M - 1;
        float r6[NRR];
        #pragma unroll
        for (int r = 0; r < NRR; ++r) r6[r] = rbf[(size_t)grow * NRR + r];
        #pragma unroll 8
        for (int hh = 0; hh < 64; ++hh) {
            int h = half * 64 + hh;
            float a = b6s[h];
            #pragma unroll
            for (int r = 0; r < NRR; ++r) a += r6[r] * W6[r * HD + h];
            Al[e_l][h] = f2us(siluf(a));
        }
    }
    __syncthreads();

    floatx4 acc[4][4]; ZERO_ACC4(acc);
    store_bh(r0, Bl, tid); __syncthreads();
    mfma_kh(Al, Bl, acc, 0, wr, wc_, lhi, llo);
    __syncthreads();
    store_bh(r1, Bl, tid); __syncthreads();
    mfma_kh(Al, Bl, acc, 1, wr, wc_, lhi, llo);

    #pragma unroll
    for (int tm = 0; tm < 4; ++tm)
        #pragma unroll
        for (int q = 0; q < 4; ++q) {
            int grow = row0 + wr * 64 + tm * 16 + lhi * 4 + q;
            if (grow >= M) continue;
            int zi = z[ii[grow]], zj = z[jj[grow]];
            #pragma unroll
            for (int tn = 0; tn < 4; ++tn) {
                int coll = wc_ * 64 + tn * 16 + llo;
                float t = acc[tm][tn][q] + A0[zi * HD + coll] + A1[zj * HD + coll] + emb_b[coll];
                float v = siluf(t);
                Xb[(size_t)grow * HD + coll] = f2us(v);
            }
        }
}

// ---------------------------------------------------------------------------
// kjcb: Cb = bf16( silu(x@Wkj+b) * rbfp )   (Wkj in fragment order)
// ---------------------------------------------------------------------------
__global__ __launch_bounds__(256, 3)
void kjcb_w(const ushort_t* __restrict__ Xb, const ushort_t* __restrict__ Wkj,
            const float* __restrict__ bkj, const float* __restrict__ rbf,
            const float* __restrict__ Wr6, ushort_t* __restrict__ Cb, int M)
{
    __shared__ float W6s[NRR * HD];
    __shared__ float bkjS[HD];
    const int tid = threadIdx.x, wave = tid >> 6, lane = tid & 63;
    const int llo = lane & 15, lhi = lane >> 4;
    for (int i = tid; i < NRR * HD; i += 256) W6s[i] = Wr6[i];
    if (tid < HD) bkjS[tid] = bkj[tid];
    __syncthreads();
    const int row0 = (blockIdx.x * 4 + wave) * 16;
    if (row0 >= M) return;

    short8 af[4];
    #pragma unroll
    for (int kc = 0; kc < 4; ++kc)
        af[kc] = *(const short8*)(Xb + (size_t)(row0 + llo) * HD + kc * 32 + lhi * 8);

    short8 nb[2][8];
    #pragma unroll
    for (int d = 0; d < 2; ++d)
        #pragma unroll
        for (int tn = 0; tn < 8; ++tn) nb[d][tn] = ldfrag(Wkj, d * 8 + tn, lane);

    float rb[4][NRR];
    {
        const float* rp = rbf + (size_t)(row0 + lhi * 4) * NRR;
        #pragma unroll
        for (int q = 0; q < 4; ++q)
            #pragma unroll
            for (int r = 0; r < NRR; ++r) rb[q][r] = rp[q * NRR + r];
    }

    floatx4 acc[8]; ZERO_ACC8(acc);
    #pragma unroll
    for (int kc = 0; kc < 4; ++kc) {
        short8 bq[8];
        #pragma unroll
        for (int tn = 0; tn < 8; ++tn) bq[tn] = nb[kc & 1][tn];
        if (kc + 2 < 4) {
            #pragma unroll
            for (int tn = 0; tn < 8; ++tn) nb[kc & 1][tn] = ldfrag(Wkj, (kc + 2) * 8 + tn, lane);
        }
        #pragma unroll
        for (int tn = 0; tn < 8; ++tn)
            acc[tn] = __builtin_amdgcn_mfma_f32_16x16x32_bf16(af[kc], bq[tn], acc[tn], 0, 0, 0);
    }
    #pragma unroll
    for (int tn = 0; tn < 8; ++tn) {
        int col = tn * 16 + llo;
        #pragma unroll
        for (int q = 0; q < 4; ++q) {
            int grow = row0 + lhi * 4 + q;
            if (grow >= M) continue;
            float rpv = 0.f;
            #pragma unroll
            for (int r = 0; r < NRR; ++r) rpv += rb[q][r] * W6s[r * HD + col];
            Cb[(size_t)grow * HD + col] = f2us(siluf(acc[tn][q] + bkjS[col]) * rpv);
        }
    }
}

// ---------------------------------------------------------------------------
// megaK v15: f32 X stream ELIMINATED (R13/R14 counters: FETCH 105 + WRITE 75
// = 180 MB at dur*BW == achieved-bandwidth bound -> cut traffic).
//  - s==2 residual reads Xb (bf16, L2-hot: phase-2 af already pulls these
//    rows); consistent with every other consumer of x (all use Xb).
//  - X f32 write dropped: WRITE 75 -> ~26 MB, FETCH 105 -> ~55 MB.
// In-place safety unchanged: block reads its 16 Xb rows before overwriting.
// OCCUPANCY LESSON (R4, R10): (256,5) spilled both times; (256,4) at
// 64 VGPR is the operating point.
// ---------------------------------------------------------------------------
__global__ __launch_bounds__(256, 4)
void megaK_w(const ushort_t* __restrict__ sps, const ushort_t* __restrict__ Cb,
             const int* __restrict__ toffs, const int* __restrict__ ekjs,
             const ushort_t* __restrict__ Xb,
             const ushort_t* __restrict__ Wm,
             const ushort_t* __restrict__ Wji, const float* __restrict__ bjig,
             const ushort_t* __restrict__ Wc, const float* __restrict__ Bc,
             ushort_t* __restrict__ Xbo)
{
    __shared__ ushort_t Ga[16384];        // 32KB; At/Ct alias the head in phase 0
    const int tid = threadIdx.x, wave = tid >> 6, lane = tid & 63;
    const int llo = lane & 15, lhi = lane >> 4;
    const int tn0 = wave * 2, tn1 = tn0 + 1;
    const int col0 = tn0 * 16 + llo, col1 = tn1 * 16 + llo;

    ushort_t* const At = &Ga[0];          // [128][40] = 5120 ushorts
    ushort_t* const Ct = &Ga[5120];       // [128][40], k-chunk swizzled

    // biases -> registers (loads overlap phase 0)
    const float bj0 = bjig[col0], bj1 = bjig[col1];
    float bsc0[7], bsc1[7];
    #pragma unroll
    for (int s = 0; s < 7; ++s) {
        bsc0[s] = Bc[s * HD + col0];
        bsc1[s] = Bc[s * HD + col1];
    }

    const int row0 = blockIdx.x * 16;

    // ---------- phase 0: gather-GEMM into gacc ----------
    floatx4 gacc[8][2];
    #pragma unroll
    for (int mt = 0; mt < 8; ++mt) {
        gacc[mt][0] = (floatx4){0.f,0.f,0.f,0.f};
        gacc[mt][1] = (floatx4){0.f,0.f,0.f,0.f};
    }
    {
        int tf[17];
        #pragma unroll
        for (int i2 = 0; i2 <= 16; ++i2)
            tf[i2] = __builtin_amdgcn_readfirstlane(toffs[row0 + i2]);
        const int K0 = tf[0], K4 = tf[16];
        const int nch = (K4 - K0 + 31) >> 5;

        const int kk8 = tid >> 3;          // triplet slot 0..31
        const int jsl = tid & 7;           // j slot 0..7
        const int h0  = (tid & 7) * 16;    // h slice for C staging
        const int ksw = (kk8 & 7) | (((kk8 >> 3) ^ (tid & 3)) << 3);
        const int rs0 = (tn0) & 3;
        const int rs1 = (tn1) & 3;

        for (int c = 0; c < nch; ++c) {
            const int kg = K0 + c * 32 + kk8;
            const bool va = kg < K4;

            ushort8v cv0 = {0,0,0,0,0,0,0,0}, cv1 = {0,0,0,0,0,0,0,0};
            ushort_t sv = 0; int eid = 0;
            if (va) {
                const int crow = ekjs[kg];
                cv0 = *(const ushort8v*)(Cb + (size_t)crow * HD + h0);
                cv1 = *(const ushort8v*)(Cb + (size_t)crow * HD + h0 + 8);
                sv  = sps[(size_t)kg * NBB + jsl];
                #pragma unroll
                for (int e2 = 1; e2 <= 16; ++e2) eid += (kg >= tf[e2]) ? 1 : 0;
            }

            {
                unsigned long long* Az = (unsigned long long*)At;
                #pragma unroll
                for (int z = 0; z < 5; ++z) Az[tid * 5 + z] = 0ULL;
            }
            __syncthreads();

            #pragma unroll
            for (int m = 0; m < 8; ++m) {
                Ct[(h0 + m) * 40 + ksw]     = cv0[m];
                Ct[(h0 + 8 + m) * 40 + ksw] = cv1[m];
            }
            if (va) At[(eid * 8 + jsl) * 40 + kk8] = sv;
            __syncthreads();

            {
                short8 bf0 = *(const short8*)&Ct[col0 * 40 + ((lhi ^ rs0) << 3)];
                short8 bf1 = *(const short8*)&Ct[col1 * 40 + ((lhi ^ rs1) << 3)];
                #pragma unroll
                for (int mt = 0; mt < 8; ++mt) {
                    short8 afm = *(const short8*)&At[(mt * 16 + llo) * 40 + lhi * 8];
                    gacc[mt][0] = __builtin_amdgcn_mfma_f32_16x16x32_bf16(afm, bf0, gacc[mt][0], 0, 0, 0);
                    gacc[mt][1] = __builtin_amdgcn_mfma_f32_16x16x32_bf16(afm, bf1, gacc[mt][1], 0, 0, 0);
                }
            }
            __syncthreads();
        }
    }

    // ---------- flush gacc -> Ga (phase-1 A layout, same swizzle) ----------
    #pragma unroll
    for (int mt = 0; mt < 8; ++mt) {
        const int el = mt * 2 + (lhi >> 1);
        const int jb = (lhi & 1) * 4;
        const int sw = (el & 7) << 3;
        #pragma unroll
        for (int nt2 = 0; nt2 < 2; ++nt2) {
            const int h  = wave * 32 + nt2 * 16 + llo;
            const int hx = h ^ sw;
            #pragma unroll
            for (int q = 0; q < 4; ++q)
                Ga[el * 1024 + (jb + q) * 128 + hx] = f2us(gacc[mt][nt2][q]);
        }
    }
    __syncthreads();

    // ---------- phase 1: K=1024 GEMM (A from swizzled LDS) ----------
    floatx4 m0 = {0.f,0.f,0.f,0.f}, m1 = {0.f,0.f,0.f,0.f};
    {
        const int abase = llo << 10;
        const int aswz  = llo & 7;
        short8 ap[2]; short8 bp[4][2];
        #pragma unroll
        for (int d = 0; d < 2; ++d)
            ap[d] = *(const short8*)&Ga[abase + ((((d << 2) + lhi) ^ aswz) << 3)];
        #pragma unroll
        for (int d = 0; d < 4; ++d) {
            bp[d][0] = ldfrag(Wm, d * 8 + tn0, lane);
            bp[d][1] = ldfrag(Wm, d * 8 + tn1, lane);
        }
        __builtin_amdgcn_s_setprio(1);
        #pragma unroll
        for (int kc = 0; kc < 32; ++kc) {
            short8 a  = ap[kc & 1];
            short8 b0 = bp[kc & 3][0], b1 = bp[kc & 3][1];
            if (kc + 2 < 32)
                ap[kc & 1] = *(const short8*)&Ga[abase + (((((kc + 2) << 2) + lhi) ^ aswz) << 3)];
            if (kc + 4 < 32) {
                bp[kc & 3][0] = ldfrag(Wm, (kc + 4) * 8 + tn0, lane);
                bp[kc & 3][1] = ldfrag(Wm, (kc + 4) * 8 + tn1, lane);
            }
            m0 = __builtin_amdgcn_mfma_f32_16x16x32_bf16(a, b0, m0, 0, 0, 0);
            m1 = __builtin_amdgcn_mfma_f32_16x16x32_bf16(a, b1, m1, 0, 0, 0);
        }
        __builtin_amdgcn_s_setprio(0);
    }
    __syncthreads();   // Ga is dead past here; Tw (alias) becomes live

    ushort_t (*Tw)[136] = (ushort_t (*)[136])&Ga[0];

    // ---------- phase 2: x_ji GEMM; hin = silu(.)+m kept in registers ----------
    float cur0[4], cur1[4], res0[4], res1[4], trk0[4], trk1[4];
    short8 nb[2][2];
    #pragma unroll
    for (int d = 0; d < 2; ++d) {
        nb[d][0] = ldfrag(Wji, d * 8 + tn0, lane);
        nb[d][1] = ldfrag(Wji, d * 8 + tn1, lane);
    }
    {
        short8 af[4];
        #pragma unroll
        for (int kc = 0; kc < 4; ++kc)
            af[kc] = *(const short8*)(Xb + (size_t)(row0 + llo) * HD + kc * 32 + lhi * 8);
        floatx4 a0 = {0.f,0.f,0.f,0.f}, a1 = {0.f,0.f,0.f,0.f};
        #pragma unroll
        for (int kc = 0; kc < 4; ++kc) {
            short8 b0 = nb[kc & 1][0], b1 = nb[kc & 1][1];
            {   // prefetch seg kc+2 (crosses into chain stage 0 weights)
                const int ps = kc + 2;
                const ushort_t* W = (ps < 4) ? Wji : Wc;
                nb[kc & 1][0] = ldfrag(W, (ps & 3) * 8 + tn0, lane);
                nb[kc & 1][1] = ldfrag(W, (ps & 3) * 8 + tn1, lane);
            }
            a0 = __builtin_amdgcn_mfma_f32_16x16x32_bf16(af[kc], b0, a0, 0, 0, 0);
            a1 = __builtin_amdgcn_mfma_f32_16x16x32_bf16(af[kc], b1, a1, 0, 0, 0);
        }
        #pragma unroll
        for (int q = 0; q < 4; ++q) {
            res0[q] = siluf(a0[q] + bj0) + m0[q];
            res1[q] = siluf(a1[q] + bj1) + m1[q];
            cur0[q] = res0[q]; cur1[q] = res1[q];
        }
    }

    // prefetch X residual from Xb (bf16, L2-hot; consumed at chain stage s==2)
    float xr0[4], xr1[4];
    #pragma unroll
    for (int q = 0; q < 4; ++q) {
        int grow = row0 + lhi * 4 + q;
        xr0[q] = us2f(Xb[(size_t)grow * HD + col0]);
        xr1[q] = us2f(Xb[(size_t)grow * HD + col1]);
    }

    // ---------- chain stages (7) ----------
    #pragma unroll
    for (int s = 0; s < 7; ++s) {
        #pragma unroll
        for (int q = 0; q < 4; ++q) {
            Tw[lhi * 4 + q][col0] = f2us(cur0[q]);
            Tw[lhi * 4 + q][col1] = f2us(cur1[q]);
        }
        __syncthreads();

        floatx4 a0 = {0.f,0.f,0.f,0.f}, a1 = {0.f,0.f,0.f,0.f};
        const int sg0 = 4 + s * 4;
        #pragma unroll
        for (int kc = 0; kc < 4; ++kc) {
            const int seg = sg0 + kc;
            short8 a8 = *(const short8*)&Tw[llo][kc * 32 + lhi * 8];
            short8 b0 = nb[seg & 1][0], b1 = nb[seg & 1][1];
            if (seg + 2 < 32) {
                const int ps = seg + 2;
                const ushort_t* W = Wc + (size_t)((ps - 4) >> 2) * MSZ;
                nb[seg & 1][0] = ldfrag(W, (ps & 3) * 8 + tn0, lane);
                nb[seg & 1][1] = ldfrag(W, (ps & 3) * 8 + tn1, lane);
            }
            a0 = __builtin_amdgcn_mfma_f32_16x16x32_bf16(a8, b0, a0, 0, 0, 0);
            a1 = __builtin_amdgcn_mfma_f32_16x16x32_bf16(a8, b1, a1, 0, 0, 0);
        }
        __syncthreads();

        #pragma unroll
        for (int q = 0; q < 4; ++q) {
            float t0v = siluf(a0[q] + bsc0[s]);
            float t1v = siluf(a1[q] + bsc1[s]);
            if (s == 0)      { cur0[q] = t0v; cur1[q] = t1v; }
            else if (s == 1) { cur0[q] = t0v + res0[q]; cur1[q] = t1v + res1[q]; }
            else if (s == 2) {
                cur0[q] = t0v + xr0[q];
                cur1[q] = t1v + xr1[q];
                trk0[q] = cur0[q]; trk1[q] = cur1[q];
            }
            else if (s == 3 || s == 5) { cur0[q] = t0v; cur1[q] = t1v; }
            else {
                cur0[q] = t0v + trk0[q]; cur1[q] = t1v + trk1[q];
                trk0[q] = cur0[q]; trk1[q] = cur1[q];
            }
        }
    }

    #pragma unroll
    for (int q = 0; q < 4; ++q) {
        int grow = row0 + lhi * 4 + q;
        size_t o = (size_t)grow * HD;
        Xbo[o + col0] = f2us(cur0[q]);
        Xbo[o + col1] = f2us(cur1[q]);
    }
}

// ---------------------------------------------------------------------------
// gatherT v2: ring-pipelined CSR gather (R3 recipe).
// ---------------------------------------------------------------------------
__global__ __launch_bounds__(256)
void gatherT_k(const ushort_t* __restrict__ Xb, const float* __restrict__ rbf,
               const float* __restrict__ Wr6, const int* __restrict__ eoffs,
               const int* __restrict__ esorted, ushort_t* __restrict__ TA, int M)
{
    __shared__ float W6s[NRR * HD];
    const int tid = threadIdx.x, wave = tid >> 6, lane = tid & 63;
    for (int i = tid; i < NRR * HD; i += 256) W6s[i] = Wr6[i];
    __syncthreads();

    const int c0 = lane * 2;
    float w0[NRR], w1[NRR];
    #pragma unroll
    for (int r = 0; r < NRR; ++r) {
        w0[r] = W6s[r * HD + c0];
        w1[r] = W6s[r * HD + c0 + 1];
    }
    const uint_t* __restrict__ Xb32 = (const uint_t*)Xb;

    int a0 = (blockIdx.x * 4 + wave) * 2;
    #pragma unroll 1
    for (int s = 0; s < 2; ++s) {
        int a = a0 + s;
        if (a >= M) return;
        float acc0 = 0.f, acc1 = 0.f;
        const int k0 = __builtin_amdgcn_readfirstlane(eoffs[a]);
        const int k1 = __builtin_amdgcn_readfirstlane(eoffs[a + 1]);

        uint_t xv[4]; float rb[4][NRR];
        #pragma unroll
        for (int p = 0; p < 4; ++p)
            if (k0 + p < k1) {
                const int e = __builtin_amdgcn_readfirstlane(esorted[k0 + p]);
                xv[p] = Xb32[(size_t)e * 64 + lane];
                #pragma unroll
                for (int r = 0; r < NRR; ++r) rb[p][r] = rbf[(size_t)e * NRR + r];
            }

        for (int base = k0; base < k1; base += 4) {
            #pragma unroll
            for (int p = 0; p < 4; ++p) {
                const int k = base + p;
                if (k < k1) {
                    const uint_t xc = xv[p];
                    float rp0 = 0.f, rp1 = 0.f;
                    #pragma unroll
                    for (int r = 0; r < NRR; ++r) {
                        rp0 += rb[p][r] * w0[r];
                        rp1 += rb[p][r] * w1[r];
                    }
                    if (k + 4 < k1) {
                        const int en = __builtin_amdgcn_readfirstlane(esorted[k + 4]);
                        xv[p] = Xb32[(size_t)en * 64 + lane];
                        #pragma unroll
                        for (int r = 0; r < NRR; ++r) rb[p][r] = rbf[(size_t)en * NRR + r];
                    }
                    acc0 += rp0 * us2f((ushort_t)(xc & 0xffffu));
                    acc1 += rp1 * __builtin_bit_cast(float, xc & 0xffff0000u);
                }
            }
        }
        TA[(size_t)a * HD + c0]     = f2us(acc0);
        TA[(size_t)a * HD + c0 + 1] = f2us(acc1);
    }
}

__global__ __launch_bounds__(256, 3)
void atomchain_w(const ushort_t* __restrict__ TA, const ushort_t* __restrict__ Wl,
                 const float* __restrict__ bl, const float* __restrict__ wout,
                 float* __restrict__ P, int M)
{
    __shared__ float blS[3 * HD];
    __shared__ float woS[HD];
    __shared__ ushort_t T[4][16][136];
    const int tid = threadIdx.x, wave = tid >> 6, lane = tid & 63;
    const int llo = lane & 15, lhi = lane >> 4;
    for (int i = tid; i < 3 * HD; i += 256) blS[i] = bl[i];
    if (tid < HD) woS[tid] = wout[tid];
    __syncthreads();
    const int row0 = (blockIdx.x * 4 + wave) * 16;
    if (row0 >= M) return;
    ushort_t (*Tw)[136] = T[wave];

    short8 nb[2][8];
    #pragma unroll
    for (int d = 0; d < 2; ++d)
        #pragma unroll
        for (int tn = 0; tn < 8; ++tn) nb[d][tn] = ldfrag(Wl, d * 8 + tn, lane);

    #pragma unroll
    for (int s = 0; s < 3; ++s) {
        short8 af[4];
        if (s == 0) {
            #pragma unroll
            for (int kc = 0; kc < 4; ++kc)
                af[kc] = *(const short8*)(TA + (size_t)(row0 + llo) * HD + kc * 32 + lhi * 8);
        } else {
            #pragma unroll
            for (int kc = 0; kc < 4; ++kc)
                af[kc] = *(const short8*)&Tw[llo][kc * 32 + lhi * 8];
        }
        floatx4 acc[8]; ZERO_ACC8(acc);
        #pragma unroll
        for (int kc = 0; kc < 4; ++kc) {
            const int seg = s * 4 + kc;
            short8 bq[8];
            #pragma unroll
            for (int tn = 0; tn < 8; ++tn) bq[tn] = nb[seg & 1][tn];
            if (seg + 2 < 12) {
                const int ps = seg + 2;
                const ushort_t* W = Wl + (size_t)(ps >> 2) * MSZ;
                #pragma unroll
                for (int tn = 0; tn < 8; ++tn)
                    nb[seg & 1][tn] = ldfrag(W, (ps & 3) * 8 + tn, lane);
            }
            #pragma unroll
            for (int tn = 0; tn < 8; ++tn)
                acc[tn] = __builtin_amdgcn_mfma_f32_16x16x32_bf16(af[kc], bq[tn], acc[tn], 0, 0, 0);
        }
        if (s < 2) {
            wave_lds_fence();
            #pragma unroll
            for (int tn = 0; tn < 8; ++tn) {
                int col = tn * 16 + llo;
                #pragma unroll
                for (int q = 0; q < 4; ++q)
                    Tw[lhi * 4 + q][col] = f2us(siluf(acc[tn][q] + blS[s * HD + col]));
            }
            wave_lds_fence();
        } else {
            #pragma unroll
            for (int q = 0; q < 4; ++q) {
                float v = 0.f;
                #pragma unroll
                for (int tn = 0; tn < 8; ++tn) {
                    int col = tn * 16 + llo;
                    v += siluf(acc[tn][q] + blS[2 * HD + col]) * woS[col];
                }
                v += __shfl_xor(v, 1); v += __shfl_xor(v, 2);
                v += __shfl_xor(v, 4); v += __shfl_xor(v, 8);
                int a = row0 + lhi * 4 + q;
                if (llo == 0 && a < M) P[a] += v;
            }
        }
    }
}

// ---------------- small kernels ----------------
__global__ void emb_lin_k(const float* __restrict__ emb_table, const float* __restrict__ emb_w,
                          float* __restrict__ A0, float* __restrict__ A1)
{
    __shared__ float er[HD];
    int a = blockIdx.x, h = threadIdx.x;
    er[h] = emb_table[a * HD + h];
    __syncthreads();
    float acc0 = 0.f, acc1 = 0.f;
    #pragma unroll 8
    for (int l = 0; l < HD; ++l) {
        float e = er[l];
        acc0 += e * emb_w[l * HD + h];
        acc1 += e * emb_w[(HD + l) * HD + h];
    }
    A0[a * HD + h] = acc0;
    A1[a * HD + h] = acc1;
}

// ---------------------------------------------------------------------------
// sbf_proj6 v3: iterate over SORTED positions (coalesced plane-major writes).
// ---------------------------------------------------------------------------
__global__ void sbf_proj6_k(const float* __restrict__ sbf, const float* __restrict__ W,
                            const int* __restrict__ tsorted, ushort_t* __restrict__ sps6,
                            int nw, size_t plane)
{
    __shared__ float Ws[NBLKS * NSNR * NBB];
    for (int s = threadIdx.x; s < nw * NSNR * NBB; s += 256) Ws[s] = W[s];
    __syncthreads();
    int p = blockIdx.x * 256 + threadIdx.x;
    if (p >= NTRIP) return;
    const int t = tsorted[p];
    float sv[NSNR];
    #pragma unroll
    for (int r = 0; r < NSNR; ++r) sv[r] = sbf[(size_t)t * NSNR + r];
    for (int b = 0; b < nw; ++b) {
        float acc[NBB];
        #pragma unroll
        for (int n = 0; n < NBB; ++n) acc[n] = 0.f;
        const float* Wb = &Ws[b * NSNR * NBB];
        #pragma unroll
        for (int r = 0; r < NSNR; ++r) {
            float v = sv[r];
            #pragma unroll
            for (int n = 0; n < NBB; ++n) acc[n] += v * Wb[r * NBB + n];
        }
        ushort8v pk;
        #pragma unroll
        for (int n = 0; n < NBB; ++n) pk[n] = f2us(acc[n]);
        *(ushort8v*)(sps6 + (size_t)b * plane + (size_t)p * NBB) = pk;
    }
}

__global__ void graph_sum_k(const float* __restrict__ P, const int* __restrict__ batch,
                            float* __restrict__ outg)
{
    int a = blockIdx.x * 256 + threadIdx.x;
    if (a >= NATOMS) return;
    atomicAdd(&outg[batch[a]], P[a]);
}

// ---------------------------------------------------------------------------
extern "C" void kernel_launch(void* const* d_in, const int* in_sizes, int n_in,
                              void* d_out, int out_size, void* d_ws, size_t ws_size,
                              hipStream_t stream)
{
    const int*   z         = (const int*)  d_in[0];
    const float* rbf       = (const float*)d_in[1];
    const float* sbf       = (const float*)d_in[2];
    const int*   ii        = (const int*)  d_in[3];
    const int*   jj        = (const int*)  d_in[4];
    const int*   idx_kj    = (const int*)  d_in[5];
    const int*   idx_ji    = (const int*)  d_in[6];
    const int*   batch     = (const int*)  d_in[7];
    const float* emb_table = (const float*)d_in[8];
    const float* emb_rbf_w = (const float*)d_in[9];
    const float* emb_rbf_b = (const float*)d_in[10];
    const float* emb_w     = (const float*)d_in[11];
    const float* emb_b     = (const float*)d_in[12];
    const float* int_rbf_w = (const float*)d_in[13];
    const float* int_sbf_w = (const float*)d_in[14];
    const float* int_kj_w  = (const float*)d_in[15];
    const float* int_kj_b  = (const float*)d_in[16];
    const float* int_ji_w  = (const float*)d_in[17];
    const float* int_ji_b  = (const float*)d_in[18];
    const float* int_W     = (const float*)d_in[19];
    const float* int_bef_w = (const float*)d_in[20];
    const float* int_bef_b = (const float*)d_in[21];
    const float* int_lin_w = (const float*)d_in[22];
    const float* int_lin_b = (const float*)d_in[23];
    const float* int_aft_w = (const float*)d_in[24];
    const float* int_aft_b = (const float*)d_in[25];
    const float* out_rbf_w = (const float*)d_in[26];
    const float* out_lins_w= (const float*)d_in[27];
    const float* out_lins_b= (const float*)d_in[28];
    const float* out_w     = (const float*)d_in[29];
    float* d_outf          = (float*)d_out;

    const size_t EH = (size_t)NEDGES * HD;
    const int OFF_EMB = 0, OFF_KJ = 1, OFF_JI = 7, OFF_CHAIN = 13, OFF_OUTL = 55;

    char* base = (char*)d_ws;
    auto take = [&](size_t bytes) { char* p = base; base += (bytes + 255) & ~(size_t)255; return p; };
    ushort_t* Xb   = (ushort_t*)take(EH * 2);
    ushort_t* Cb   = (ushort_t*)take(EH * 2);
    ushort_t* TA   = (ushort_t*)take((size_t)NATOMS * HD * 2);
    float* P_atom  = (float*)take((size_t)NATOMS * 4);
    float* A0      = (float*)take(95 * HD * 4);
    float* A1      = (float*)take(95 * HD * 4);
    float* bc      = (float*)take((size_t)NBLKS * 7 * HD * 4);
    int*   counts  = (int*)  take((size_t)(NEDGES + 1) * 4);
    int*   bsum    = (int*)  take(1024 * 4);
    int*   toffs   = (int*)  take((size_t)(NEDGES + 1) * 4);
    int*   eoffs   = (int*)  take((size_t)(NATOMS + 1) * 4);
    int*   tsorted = (int*)  take((size_t)NTRIP * 4);
    int*   esorted = (int*)  take((size_t)NEDGES * 4);
    int*   tpos    = (int*)  take((size_t)NTRIP * 4);
    int*   ekjs    = (int*)  take((size_t)NTRIP * 4);
    ushort_t* w128 = (ushort_t*)take((size_t)76 * MSZ * 2);
    ushort_t* wM   = (ushort_t*)take((size_t)NBLKS * HD * 1024 * 2);

    // sps allocated last, fused 6-plane (plane-major) if workspace allows
    size_t used = (size_t)(base - (char*)d_ws);
    size_t need6 = (size_t)NTRIP * NBLKS * NBB * 2;
    int nw = (used + need6 + 256 <= ws_size) ? NBLKS : 1;
    ushort_t* sps = (ushort_t*)take((size_t)NTRIP * nw * NBB * 2);
    const size_t plane = (size_t)NTRIP * NBB;

    auto zero = [&](float* p, size_t n) {
        zerof_k<<<((int)n + 255) / 256, 256, 0, stream>>>(p, (int)n);
    };

    // ---------------- weight prep ----------------
    transp128_k<<< 1, 256, 0, stream>>>(emb_w + 2 * MSZ, w128 + (size_t)OFF_EMB * MSZ);
    transp128s_k<<< 6, 256, 0, stream>>>(int_kj_w,   w128 + (size_t)OFF_KJ  * MSZ);
    transp128s_k<<< 6, 256, 0, stream>>>(int_ji_w,   w128 + (size_t)OFF_JI  * MSZ);
    for (int b = 0; b < NBLKS; ++b) {
        transp128s_k<<<2, 256, 0, stream>>>(int_bef_w + (size_t)b * 2 * MSZ,
                                            w128 + (size_t)(OFF_CHAIN + b * 7) * MSZ);
        transp128s_k<<<1, 256, 0, stream>>>(int_lin_w + (size_t)b * MSZ,
                                            w128 + (size_t)(OFF_CHAIN + b * 7 + 2) * MSZ);
        transp128s_k<<<4, 256, 0, stream>>>(int_aft_w + (size_t)b * 4 * MSZ,
                                            w128 + (size_t)(OFF_CHAIN + b * 7 + 3) * MSZ);
    }
    transp128s_k<<<21, 256, 0, stream>>>(out_lins_w, w128 + (size_t)OFF_OUTL * MSZ);
    castWMs_k<<<(NBLKS * HD * 1024 + 255) / 256, 256, 0, stream>>>(int_W, wM, NBLKS * HD * 1024);
    pack_bc_k<<<NBLKS, 256, 0, stream>>>(int_bef_b, int_lin_b, int_aft_b, bc);

    // ---------------- CSR builds ----------------
    {
        zeroi_k<<<(NEDGES + 255) / 256, 256, 0, stream>>>(counts, NEDGES);
        hist_k<<<(NTRIP + 255) / 256, 256, 0, stream>>>(idx_ji, NTRIP, counts);
        int nb = (NEDGES + 255) / 256;
        blksum_k<<<nb, 256, 0, stream>>>(counts, NEDGES, bsum);
        scanb_k<<<1, 1024, 0, stream>>>(bsum, nb);
        scanfin_k<<<nb, 256, 0, stream>>>(counts, NEDGES, bsum, toffs);
        zeroi_k<<<(NEDGES + 255) / 256, 256, 0, stream>>>(counts, NEDGES);
        fill_k<<<(NTRIP + 255) / 256, 256, 0, stream>>>(idx_ji, NTRIP, toffs, counts, tsorted);
        invperm_k<<<(NTRIP + 255) / 256, 256, 0, stream>>>(tsorted, idx_kj, tpos, ekjs, NTRIP);
    }
    {
        zeroi_k<<<(NATOMS + 255) / 256, 256, 0, stream>>>(counts, NATOMS);
        hist_k<<<(NEDGES + 255) / 256, 256, 0, stream>>>(ii, NEDGES, counts);
        int nb = (NATOMS + 255) / 256;
        blksum_k<<<nb, 256, 0, stream>>>(counts, NATOMS, bsum);
        scanb_k<<<1, 1024, 0, stream>>>(bsum, nb);
        scanfin_k<<<nb, 256, 0, stream>>>(counts, NATOMS, bsum, eoffs);
        zeroi_k<<<(NATOMS + 255) / 256, 256, 0, stream>>>(counts, NATOMS);
        fill_k<<<(NEDGES + 255) / 256, 256, 0, stream>>>(ii, NEDGES, eoffs, counts, esorted);
    }

    const int EGRID = (NEDGES + 127) / 128;
    const int EW    = (NEDGES / 16 + 3) / 4;
    const int AW    = (NATOMS / 16 + 3) / 4;
    const int GW    = (NATOMS / 2 + 3) / 4;
    const int MW    = NEDGES / 16;   // 6250, exact
    auto out_block = [&](int k) {
        gatherT_k<<<GW, 256, 0, stream>>>(
            Xb, rbf, out_rbf_w + (size_t)k * NRR * HD, eoffs, esorted, TA, NATOMS);
        atomchain_w<<<AW, 256, 0, stream>>>(
            TA, w128 + (size_t)(OFF_OUTL + 3 * k) * MSZ,
            out_lins_b + (size_t)k * 3 * HD, out_w + (size_t)k * HD, P_atom, NATOMS);
    };

    // ---------------- Embedding ----------------
    emb_lin_k<<<95, HD, 0, stream>>>(emb_table, emb_w, A0, A1);
    emb_chain_k<<<EGRID, 256, 0, stream>>>(
        rbf, emb_rbf_w, emb_rbf_b, w128 + (size_t)OFF_EMB * MSZ,
        A0, A1, emb_b, z, ii, jj, Xb, NEDGES);

    zero(P_atom, NATOMS);
    out_block(0);

    // fused sbf projection (one pass over sbf for all 6 blocks, plane-major,
    // sorted-position order -> coalesced writes)
    if (nw == NBLKS)
        sbf_proj6_k<<<(NTRIP + 255) / 256, 256, 0, stream>>>(
            sbf, int_sbf_w, tsorted, sps, NBLKS, plane);

    // ---------------- Interaction blocks ----------------
    for (int b = 0; b < NBLKS; ++b) {
        if (nw != NBLKS)
            sbf_proj6_k<<<(NTRIP + 255) / 256, 256, 0, stream>>>(
                sbf, int_sbf_w + (size_t)b * NSNR * NBB, tsorted, sps, 1, plane);

        kjcb_w<<<EW, 256, 0, stream>>>(
            Xb, w128 + (size_t)(OFF_KJ + b) * MSZ, int_kj_b + (size_t)b * HD,
            rbf, int_rbf_w + (size_t)b * NRR * HD, Cb, NEDGES);

        megaK_w<<<MW, 256, 0, stream>>>(
            sps + (nw == NBLKS ? (size_t)b * plane : 0), Cb, toffs, ekjs, Xb,
            wM + (size_t)b * HD * 1024,
            w128 + (size_t)(OFF_JI + b) * MSZ, int_ji_b + (size_t)b * HD,
            w128 + (size_t)(OFF_CHAIN + b * 7) * MSZ, bc + (size_t)b * 7 * HD,
            Xb);

        out_block(b + 1);
    }

    // ---------------- Final graph reduction ----------------
    zero(d_outf, NGRAPH);
    graph_sum_k<<<(NATOMS + 255) / 256, 256, 0, stream>>>(P_atom, batch, d_outf);
}